// Round 1
// baseline (24887.038 us; speedup 1.0000x reference)
//
#include <hip/hip_runtime.h>

#define T_LEN 2048
#define HID 64
#define NG 256     // 4*HID gates per layer
#define EMB 128

__device__ __forceinline__ float sigf(float x) {
    return 1.0f / (1.0f + __expf(-x));
}
__device__ __forceinline__ float tanh_fast(float x) {
    // tanh(x) = 2*sigmoid(2x)-1; saturates correctly for large |x|
    return 2.0f / (1.0f + __expf(-2.0f * x)) - 1.0f;
}

// One block per batch element. 768 threads = 3 pipeline stages x 256 threads.
// Stage l computes layer l at t = s - l (software wavefront over scan index s).
// Hidden states live in depth-2 LDS rings; no global intermediates needed.
__global__ __launch_bounds__(768) void lstm3_fused(
    const float* __restrict__ x,
    const float* __restrict__ Wih0, const float* __restrict__ Whh0,
    const float* __restrict__ bih0, const float* __restrict__ bhh0,
    const float* __restrict__ Wih1, const float* __restrict__ Whh1,
    const float* __restrict__ bih1, const float* __restrict__ bhh1,
    const float* __restrict__ Wih2, const float* __restrict__ Whh2,
    const float* __restrict__ bih2, const float* __restrict__ bhh2,
    const float* __restrict__ fcW,  const float* __restrict__ fcb,
    float* __restrict__ out)
{
    const int b     = blockIdx.x;
    const int tid   = threadIdx.x;
    const int stage = tid >> 8;   // 0,1,2 — wave-uniform (4 waves per stage)
    const int j     = tid & 255;  // gate index within stage
    const int cls   = j >> 6;     // 0=i,1=f,2=g,3=o — wave-uniform

    __shared__ __align__(16) float h0r[2][HID];
    __shared__ __align__(16) float h1r[2][HID];
    __shared__ __align__(16) float h2r[2][HID];
    __shared__ float g0[NG], g1[NG], g2[NG];
    __shared__ float hfin[HID];

    if (tid < HID) {
        h0r[0][tid] = 0.f; h0r[1][tid] = 0.f;
        h1r[0][tid] = 0.f; h1r[1][tid] = 0.f;
        h2r[0][tid] = 0.f; h2r[1][tid] = 0.f;
    }

    // Per-thread weight rows in registers (~128 VGPRs of weights).
    float wih[HID], whh[HID];
    float wx0 = 0.f, bj = 0.f;
    if (stage == 0) {
        wx0 = Wih0[j];               // Wih0 is [256,1]
        bj  = bih0[j] + bhh0[j];
        #pragma unroll 16
        for (int k = 0; k < HID; ++k) { whh[k] = Whh0[j * HID + k]; wih[k] = 0.f; }
    } else {
        const float* Wi = (stage == 1) ? Wih1 : Wih2;
        const float* Wh = (stage == 1) ? Whh1 : Whh2;
        const float* bi = (stage == 1) ? bih1 : bih2;
        const float* bh = (stage == 1) ? bhh1 : bhh2;
        bj = bi[j] + bh[j];
        #pragma unroll 16
        for (int k = 0; k < HID; ++k) { wih[k] = Wi[j * HID + k]; whh[k] = Wh[j * HID + k]; }
    }

    float c = 0.f;                      // cell state, threads j<64 of each stage
    float xcur  = (stage == 0) ? x[b * T_LEN] : 0.f;  // x layout [B,1,T]
    float xnext = 0.f;

    __syncthreads();

    for (int s = 0; s < T_LEN + 2; ++s) {
        const int rd = (s + 1) & 1;     // ring slot written at iter s-1
        const int wr = s & 1;

        // Prefetch next timestep's x (stage 0 only) — hides global latency.
        if (stage == 0 && s + 1 < T_LEN) xnext = x[b * T_LEN + s + 1];

        bool act;
        if (stage == 0) {
            act = (s < T_LEN);
            if (act) {
                float acc = bj + wx0 * xcur;
                const float* h = h0r[rd];
                #pragma unroll
                for (int k = 0; k < HID; ++k) acc += whh[k] * h[k];
                g0[j] = (cls == 2) ? tanh_fast(acc) : sigf(acc);
            }
        } else if (stage == 1) {
            act = (s >= 1 && s < T_LEN + 1);
            if (act) {
                float acc = bj;
                const float* xin = h0r[rd];   // h0[t = s-1]
                const float* h   = h1r[rd];   // h1[t-1]
                #pragma unroll
                for (int k = 0; k < HID; ++k) acc += wih[k] * xin[k];
                #pragma unroll
                for (int k = 0; k < HID; ++k) acc += whh[k] * h[k];
                g1[j] = (cls == 2) ? tanh_fast(acc) : sigf(acc);
            }
        } else {
            act = (s >= 2);
            if (act) {
                float acc = bj;
                const float* xin = h1r[rd];   // h1[t = s-2]
                const float* h   = h2r[rd];   // h2[t-1]
                #pragma unroll
                for (int k = 0; k < HID; ++k) acc += wih[k] * xin[k];
                #pragma unroll
                for (int k = 0; k < HID; ++k) acc += whh[k] * h[k];
                g2[j] = (cls == 2) ? tanh_fast(acc) : sigf(acc);
            }
        }
        __syncthreads();   // gates (activated) visible

        if (j < HID && act) {
            const float* gg = (stage == 0) ? g0 : (stage == 1) ? g1 : g2;
            float iv = gg[j], fv = gg[HID + j], gv = gg[2 * HID + j], ov = gg[3 * HID + j];
            c = fv * c + iv * gv;
            float h = ov * tanh_fast(c);
            float* ring = (stage == 0) ? h0r[wr] : (stage == 1) ? h1r[wr] : h2r[wr];
            ring[j] = h;
            if (stage == 2 && s == T_LEN + 1) hfin[j] = h;  // t == T-1
        }
        __syncthreads();   // ring writes visible for next iteration
        xcur = xnext;
    }

    // Final FC: out[b,m] = fcb[m] + sum_k fcW[m,k] * h2_last[k]
    if (tid < EMB) {
        float acc = fcb[tid];
        #pragma unroll 16
        for (int k = 0; k < HID; ++k) acc += fcW[tid * HID + k] * hfin[k];
        out[b * EMB + tid] = acc;
    }
}

extern "C" void kernel_launch(void* const* d_in, const int* in_sizes, int n_in,
                              void* d_out, int out_size, void* d_ws, size_t ws_size,
                              hipStream_t stream) {
    const float* x    = (const float*)d_in[0];
    const float* Wih0 = (const float*)d_in[1];
    const float* Whh0 = (const float*)d_in[2];
    const float* bih0 = (const float*)d_in[3];
    const float* bhh0 = (const float*)d_in[4];
    const float* Wih1 = (const float*)d_in[5];
    const float* Whh1 = (const float*)d_in[6];
    const float* bih1 = (const float*)d_in[7];
    const float* bhh1 = (const float*)d_in[8];
    const float* Wih2 = (const float*)d_in[9];
    const float* Whh2 = (const float*)d_in[10];
    const float* bih2 = (const float*)d_in[11];
    const float* bhh2 = (const float*)d_in[12];
    const float* fcW  = (const float*)d_in[13];
    const float* fcb  = (const float*)d_in[14];
    float* out = (float*)d_out;

    lstm3_fused<<<dim3(256), dim3(768), 0, stream>>>(
        x, Wih0, Whh0, bih0, bhh0,
        Wih1, Whh1, bih1, bhh1,
        Wih2, Whh2, bih2, bhh2,
        fcW, fcb, out);
}

// Round 2
// 2314.986 us; speedup vs baseline: 10.7504x; 10.7504x over previous
//
#include <hip/hip_runtime.h>

#define T_LEN 2048
#define HID 64
#define NG 256     // 4*HID gates per layer
#define EMB 128

__device__ __forceinline__ float sigf(float x) {
    return 1.0f / (1.0f + __expf(-x));
}
__device__ __forceinline__ float tanh_fast(float x) {
    // tanh(x) = 2*sigmoid(2x)-1; saturates correctly for large |x|
    return 2.0f / (1.0f + __expf(-2.0f * x)) - 1.0f;
}

// One block per batch element. 768 threads = 3 pipeline stages x 256 threads.
// Stage l computes layer l at t = s - l (software wavefront over scan index s).
// Hidden states live in depth-2 LDS rings; no global intermediates.
// Weights are held in VGPRs: float4[16] arrays with FULLY unrolled load/use
// loops (partial unroll leaves dynamic indexing -> scratch spill -> 84 GB of
// HBM traffic, the Round-1 failure). launch_bounds(768,3): VGPR cap 170 so
// all 12 waves of the block fit at 3 waves/SIMD.
__global__ __launch_bounds__(768, 3) void lstm3_fused(
    const float* __restrict__ x,
    const float* __restrict__ Wih0, const float* __restrict__ Whh0,
    const float* __restrict__ bih0, const float* __restrict__ bhh0,
    const float* __restrict__ Wih1, const float* __restrict__ Whh1,
    const float* __restrict__ bih1, const float* __restrict__ bhh1,
    const float* __restrict__ Wih2, const float* __restrict__ Whh2,
    const float* __restrict__ bih2, const float* __restrict__ bhh2,
    const float* __restrict__ fcW,  const float* __restrict__ fcb,
    float* __restrict__ out)
{
    const int b     = blockIdx.x;
    const int tid   = threadIdx.x;
    const int stage = tid >> 8;   // 0,1,2 — wave-uniform (4 waves per stage)
    const int j     = tid & 255;  // gate index within stage
    const int cls   = j >> 6;     // 0=i,1=f,2=g,3=o — wave-uniform

    __shared__ __align__(16) float h0r[2][HID];
    __shared__ __align__(16) float h1r[2][HID];
    __shared__ __align__(16) float h2r[2][HID];
    __shared__ float g0[NG], g1[NG], g2[NG];
    __shared__ float hfin[HID];

    if (tid < HID) {
        h0r[0][tid] = 0.f; h0r[1][tid] = 0.f;
        h1r[0][tid] = 0.f; h1r[1][tid] = 0.f;
        h2r[0][tid] = 0.f; h2r[1][tid] = 0.f;
    }

    // Per-thread weight rows in registers: 32 float4 = 128 VGPRs.
    float4 wih4[16], whh4[16];
    float wx0 = 0.f, bj = 0.f;
    if (stage == 0) {
        wx0 = Wih0[j];               // Wih0 is [256,1]
        bj  = bih0[j] + bhh0[j];
        const float4* Wh4 = reinterpret_cast<const float4*>(Whh0 + j * HID);
        #pragma unroll
        for (int k = 0; k < 16; ++k) {
            whh4[k] = Wh4[k];
            wih4[k] = make_float4(0.f, 0.f, 0.f, 0.f);
        }
    } else {
        const float* Wi = (stage == 1) ? Wih1 : Wih2;
        const float* Wh = (stage == 1) ? Whh1 : Whh2;
        const float* bi = (stage == 1) ? bih1 : bih2;
        const float* bh = (stage == 1) ? bhh1 : bhh2;
        bj = bi[j] + bh[j];
        const float4* Wi4 = reinterpret_cast<const float4*>(Wi + j * HID);
        const float4* Wh4 = reinterpret_cast<const float4*>(Wh + j * HID);
        #pragma unroll
        for (int k = 0; k < 16; ++k) { wih4[k] = Wi4[k]; whh4[k] = Wh4[k]; }
    }

    float c = 0.f;                      // cell state (threads j<64 of each stage)
    float xcur  = (stage == 0) ? x[b * T_LEN] : 0.f;  // x layout [B,1,T]
    float xnext = 0.f;

    __syncthreads();

    for (int s = 0; s < T_LEN + 2; ++s) {
        const int rd = (s + 1) & 1;     // ring slot written at iter s-1
        const int wr = s & 1;

        // Prefetch next timestep's x (stage 0 only) — hides global latency.
        if (stage == 0 && s + 1 < T_LEN) xnext = x[b * T_LEN + s + 1];

        bool act;
        if (stage == 0) {
            act = (s < T_LEN);
            if (act) {
                float acc = bj + wx0 * xcur;
                const float4* h4 = reinterpret_cast<const float4*>(h0r[rd]);
                #pragma unroll
                for (int k = 0; k < 16; ++k) {
                    float4 hv = h4[k];
                    acc += whh4[k].x * hv.x + whh4[k].y * hv.y
                         + whh4[k].z * hv.z + whh4[k].w * hv.w;
                }
                g0[j] = (cls == 2) ? tanh_fast(acc) : sigf(acc);
            }
        } else if (stage == 1) {
            act = (s >= 1 && s < T_LEN + 1);
            if (act) {
                float acc = bj;
                const float4* x4 = reinterpret_cast<const float4*>(h0r[rd]);  // h0[t=s-1]
                const float4* h4 = reinterpret_cast<const float4*>(h1r[rd]);  // h1[t-1]
                #pragma unroll
                for (int k = 0; k < 16; ++k) {
                    float4 xv = x4[k], hv = h4[k];
                    acc += wih4[k].x * xv.x + wih4[k].y * xv.y
                         + wih4[k].z * xv.z + wih4[k].w * xv.w;
                    acc += whh4[k].x * hv.x + whh4[k].y * hv.y
                         + whh4[k].z * hv.z + whh4[k].w * hv.w;
                }
                g1[j] = (cls == 2) ? tanh_fast(acc) : sigf(acc);
            }
        } else {
            act = (s >= 2);
            if (act) {
                float acc = bj;
                const float4* x4 = reinterpret_cast<const float4*>(h1r[rd]);  // h1[t=s-2]
                const float4* h4 = reinterpret_cast<const float4*>(h2r[rd]);  // h2[t-1]
                #pragma unroll
                for (int k = 0; k < 16; ++k) {
                    float4 xv = x4[k], hv = h4[k];
                    acc += wih4[k].x * xv.x + wih4[k].y * xv.y
                         + wih4[k].z * xv.z + wih4[k].w * xv.w;
                    acc += whh4[k].x * hv.x + whh4[k].y * hv.y
                         + whh4[k].z * hv.z + whh4[k].w * hv.w;
                }
                g2[j] = (cls == 2) ? tanh_fast(acc) : sigf(acc);
            }
        }
        __syncthreads();   // gates (activated) visible

        if (j < HID && act) {
            const float* gg = (stage == 0) ? g0 : (stage == 1) ? g1 : g2;
            float iv = gg[j], fv = gg[HID + j], gv = gg[2 * HID + j], ov = gg[3 * HID + j];
            c = fv * c + iv * gv;
            float h = ov * tanh_fast(c);
            float* ring = (stage == 0) ? h0r[wr] : (stage == 1) ? h1r[wr] : h2r[wr];
            ring[j] = h;
            if (stage == 2 && s == T_LEN + 1) hfin[j] = h;  // t == T-1
        }
        __syncthreads();   // ring writes visible for next iteration
        xcur = xnext;
    }

    // Final FC: out[b,m] = fcb[m] + sum_k fcW[m,k] * h2_last[k]
    if (tid < EMB) {
        float acc = fcb[tid];
        const float4* W4 = reinterpret_cast<const float4*>(fcW + tid * HID);
        const float4* h4 = reinterpret_cast<const float4*>(hfin);
        #pragma unroll
        for (int k = 0; k < 16; ++k) {
            float4 wv = W4[k], hv = h4[k];
            acc += wv.x * hv.x + wv.y * hv.y + wv.z * hv.z + wv.w * hv.w;
        }
        out[b * EMB + tid] = acc;
    }
}

extern "C" void kernel_launch(void* const* d_in, const int* in_sizes, int n_in,
                              void* d_out, int out_size, void* d_ws, size_t ws_size,
                              hipStream_t stream) {
    const float* x    = (const float*)d_in[0];
    const float* Wih0 = (const float*)d_in[1];
    const float* Whh0 = (const float*)d_in[2];
    const float* bih0 = (const float*)d_in[3];
    const float* bhh0 = (const float*)d_in[4];
    const float* Wih1 = (const float*)d_in[5];
    const float* Whh1 = (const float*)d_in[6];
    const float* bih1 = (const float*)d_in[7];
    const float* bhh1 = (const float*)d_in[8];
    const float* Wih2 = (const float*)d_in[9];
    const float* Whh2 = (const float*)d_in[10];
    const float* bih2 = (const float*)d_in[11];
    const float* bhh2 = (const float*)d_in[12];
    const float* fcW  = (const float*)d_in[13];
    const float* fcb  = (const float*)d_in[14];
    float* out = (float*)d_out;

    lstm3_fused<<<dim3(256), dim3(768), 0, stream>>>(
        x, Wih0, Whh0, bih0, bhh0,
        Wih1, Whh1, bih1, bhh1,
        Wih2, Whh2, bih2, bhh2,
        fcW, fcb, out);
}

// Round 3
// 1738.171 us; speedup vs baseline: 14.3179x; 1.3319x over previous
//
#include <hip/hip_runtime.h>

#define T_LEN 2048
#define HID 64
#define NG 256     // 4*HID gates per layer
#define EMB 128
#define NITER (T_LEN + 4)

typedef _Float16 half2_t __attribute__((ext_vector_type(2)));
typedef _Float16 half8_t __attribute__((ext_vector_type(8)));

// v_dot2_f32_f16: 2-way f16 dot with f32 accumulate (CDNA3/4 retain this).
__device__ __forceinline__ float fdot2(half2_t a, half2_t b, float c) {
    return __builtin_amdgcn_fdot2(a, b, c, false);
}

__device__ __forceinline__ float sigf(float x) {
    return 1.0f / (1.0f + __expf(-x));
}
__device__ __forceinline__ float tanh_fast(float x) {
    return 2.0f / (1.0f + __expf(-2.0f * x)) - 1.0f;
}

// 64-MAC dot: w = 32 half2 in VGPRs, h = 64 f16 in LDS (same-address broadcast
// reads, ds_read_b128 x8). f32 accumulation throughout.
__device__ __forceinline__ float dot64(const half2_t* w, const _Float16* hbase, float acc) {
    const half8_t* h8 = reinterpret_cast<const half8_t*>(hbase);
    #pragma unroll
    for (int k = 0; k < 8; ++k) {
        half8_t hv = h8[k];
        acc = fdot2(w[4 * k + 0], half2_t{hv[0], hv[1]}, acc);
        acc = fdot2(w[4 * k + 1], half2_t{hv[2], hv[3]}, acc);
        acc = fdot2(w[4 * k + 2], half2_t{hv[4], hv[5]}, acc);
        acc = fdot2(w[4 * k + 3], half2_t{hv[6], hv[7]}, acc);
    }
    return acc;
}

// Load one 64-float weight row, convert to 32 packed half2 (f16) in VGPRs.
__device__ __forceinline__ void cvt_row(const float* __restrict__ W, int j, half2_t* dst) {
    const float4* W4 = reinterpret_cast<const float4*>(W + j * HID);
    #pragma unroll
    for (int k = 0; k < 16; ++k) {
        float4 v = W4[k];
        dst[2 * k]     = half2_t{(_Float16)v.x, (_Float16)v.y};
        dst[2 * k + 1] = half2_t{(_Float16)v.z, (_Float16)v.w};
    }
}

// One block per batch element. 768 threads = 3 stages x 256.
// Rebalanced 5-task pipeline (each task a 64-dot):
//   S0: gates0 (whh0*h0 + wx0*x)  AND  p1 = Wih1*h0   (producer-side ih-dot)
//   S1: gates1 (whh1*h1 + p1 + b) AND  p2 = Wih2*h1
//   S2: gates2 (whh2*h2 + p2 + b)
// Production schedule: h0[t] @ iter t, p1[t] @ t+1, h1[t] @ t+2, p2[t] @ t+3,
// h2[t] @ t+4. All f16 weights/h (64 VGPRs of weights -> no AGPR spill, the
// Round-2 failure); c-state, accumulators, activations, x, FC stay f32.
__global__ __launch_bounds__(768, 3) void lstm3_fused(
    const float* __restrict__ x,
    const float* __restrict__ Wih0, const float* __restrict__ Whh0,
    const float* __restrict__ bih0, const float* __restrict__ bhh0,
    const float* __restrict__ Wih1, const float* __restrict__ Whh1,
    const float* __restrict__ bih1, const float* __restrict__ bhh1,
    const float* __restrict__ Wih2, const float* __restrict__ Whh2,
    const float* __restrict__ bih2, const float* __restrict__ bhh2,
    const float* __restrict__ fcW,  const float* __restrict__ fcb,
    float* __restrict__ out)
{
    const int b     = blockIdx.x;
    const int tid   = threadIdx.x;
    const int stage = tid >> 8;   // 0,1,2 — wave-uniform
    const int j     = tid & 255;  // gate index within layer
    const int cls   = j >> 6;     // 0=i,1=f,2=g,3=o — wave-uniform

    __shared__ __align__(16) _Float16 h0f[2][HID];
    __shared__ __align__(16) _Float16 h1f[2][HID];
    __shared__ __align__(16) _Float16 h2f[2][HID];
    __shared__ float g0[NG], g1[NG], g2[NG];
    __shared__ float p1buf[2][NG], p2buf[2][NG];
    __shared__ float hfin[HID];

    if (tid < HID) {
        h0f[0][tid] = (_Float16)0.f; h0f[1][tid] = (_Float16)0.f;
        h1f[0][tid] = (_Float16)0.f; h1f[1][tid] = (_Float16)0.f;
        h2f[0][tid] = (_Float16)0.f; h2f[1][tid] = (_Float16)0.f;
    }

    half2_t wh[32];   // recurrent weights (own layer), f16 packed
    half2_t wi[32];   // next layer's ih weights (p-task), f16 packed
    float wx0 = 0.f, bj = 0.f;
    if (stage == 0) {
        wx0 = Wih0[j];               // Wih0 is [256,1]
        bj  = bih0[j] + bhh0[j];
        cvt_row(Whh0, j, wh);
        cvt_row(Wih1, j, wi);        // p1 task
    } else if (stage == 1) {
        bj = bih1[j] + bhh1[j];
        cvt_row(Whh1, j, wh);
        cvt_row(Wih2, j, wi);        // p2 task
    } else {
        bj = bih2[j] + bhh2[j];
        cvt_row(Whh2, j, wh);
    }

    float c = 0.f;                      // cell state (threads j<64 of each stage)
    const float* xp = x + b * T_LEN;    // x layout [B,1,T]
    float xcur  = xp[0];
    float xnext = 0.f;

    __syncthreads();

    for (int s = 0; s < NITER; ++s) {
        const int rd = (s + 1) & 1;     // slot written at iter s-1
        const int wr = s & 1;

        if (stage == 0 && s + 1 < T_LEN) xnext = xp[s + 1];

        bool act_main;
        if (stage == 0) {
            act_main = (s < T_LEN);                       // produces h0[s]
            const bool act_p = (s >= 1 && s <= T_LEN);    // produces p1[s-1]
            if (act_main) {
                float acc = fmaf(wx0, xcur, bj);
                acc = dot64(wh, h0f[rd], acc);            // whh0 . h0[s-1]
                g0[j] = (cls == 2) ? tanh_fast(acc) : sigf(acc);
            }
            if (act_p) {
                p1buf[wr][j] = dot64(wi, h0f[rd], 0.f);   // Wih1 . h0[s-1]
            }
        } else if (stage == 1) {
            act_main = (s >= 2 && s <= T_LEN + 1);        // produces h1[s-2]
            const bool act_p = (s >= 3 && s <= T_LEN + 2);// produces p2[s-3]
            if (act_main) {
                float acc = bj + p1buf[rd][j];            // p1[s-2]
                acc = dot64(wh, h1f[rd], acc);            // whh1 . h1[s-3]
                g1[j] = (cls == 2) ? tanh_fast(acc) : sigf(acc);
            }
            if (act_p) {
                p2buf[wr][j] = dot64(wi, h1f[rd], 0.f);   // Wih2 . h1[s-3]
            }
        } else {
            act_main = (s >= 4);                          // produces h2[s-4]
            if (act_main) {
                float acc = bj + p2buf[rd][j];            // p2[s-4]
                acc = dot64(wh, h2f[rd], acc);            // whh2 . h2[s-5]
                g2[j] = (cls == 2) ? tanh_fast(acc) : sigf(acc);
            }
        }
        __syncthreads();   // gates + p-buffers visible

        if (j < HID && act_main) {
            const float* gg = (stage == 0) ? g0 : (stage == 1) ? g1 : g2;
            float iv = gg[j], fv = gg[HID + j], gv = gg[2 * HID + j], ov = gg[3 * HID + j];
            c = fv * c + iv * gv;
            float h = ov * tanh_fast(c);
            _Float16* ring = (stage == 0) ? h0f[wr] : (stage == 1) ? h1f[wr] : h2f[wr];
            ring[j] = (_Float16)h;
            if (stage == 2 && s == NITER - 1) hfin[j] = h;   // h2[T-1], f32
        }
        __syncthreads();   // ring writes visible for next iteration
        xcur = xnext;
    }

    // Final FC (f32): out[b,m] = fcb[m] + fcW[m,:] . h2_last
    if (tid < EMB) {
        float acc = fcb[tid];
        const float4* W4 = reinterpret_cast<const float4*>(fcW + tid * HID);
        const float4* h4 = reinterpret_cast<const float4*>(hfin);
        #pragma unroll
        for (int k = 0; k < 16; ++k) {
            float4 wv = W4[k], hv = h4[k];
            acc = fmaf(wv.x, hv.x, acc);
            acc = fmaf(wv.y, hv.y, acc);
            acc = fmaf(wv.z, hv.z, acc);
            acc = fmaf(wv.w, hv.w, acc);
        }
        out[b * EMB + tid] = acc;
    }
}

extern "C" void kernel_launch(void* const* d_in, const int* in_sizes, int n_in,
                              void* d_out, int out_size, void* d_ws, size_t ws_size,
                              hipStream_t stream) {
    const float* x    = (const float*)d_in[0];
    const float* Wih0 = (const float*)d_in[1];
    const float* Whh0 = (const float*)d_in[2];
    const float* bih0 = (const float*)d_in[3];
    const float* bhh0 = (const float*)d_in[4];
    const float* Wih1 = (const float*)d_in[5];
    const float* Whh1 = (const float*)d_in[6];
    const float* bih1 = (const float*)d_in[7];
    const float* bhh1 = (const float*)d_in[8];
    const float* Wih2 = (const float*)d_in[9];
    const float* Whh2 = (const float*)d_in[10];
    const float* bih2 = (const float*)d_in[11];
    const float* bhh2 = (const float*)d_in[12];
    const float* fcW  = (const float*)d_in[13];
    const float* fcb  = (const float*)d_in[14];
    float* out = (float*)d_out;

    lstm3_fused<<<dim3(256), dim3(768), 0, stream>>>(
        x, Wih0, Whh0, bih0, bhh0,
        Wih1, Whh1, bih1, bhh1,
        Wih2, Whh2, bih2, bhh2,
        fcW, fcb, out);
}